// Round 10
// baseline (1765.998 us; speedup 1.0000x reference)
//
#include <hip/hip_runtime.h>

typedef unsigned short u16;
typedef unsigned int u32;
typedef __attribute__((ext_vector_type(8))) short bf16x8;
typedef __attribute__((ext_vector_type(4))) float f32x4;
typedef __attribute__((ext_vector_type(16))) float f32x16;
typedef __attribute__((ext_vector_type(4))) u16 u16x4;
typedef __attribute__((ext_vector_type(4))) u32 u32x4;

__device__ __forceinline__ u16 f2bf(float f) {
  u32 u = __builtin_bit_cast(u32, f);
  return (u16)((u + 0x7FFFu + ((u >> 16) & 1u)) >> 16);
}

__device__ __forceinline__ f32x4 mfma16(bf16x8 a, bf16x8 b, f32x4 c) {
  return __builtin_amdgcn_mfma_f32_16x16x32_bf16(a, b, c, 0, 0, 0);
}
__device__ __forceinline__ f32x16 mfma32(bf16x8 a, bf16x8 b, f32x16 c) {
  return __builtin_amdgcn_mfma_f32_32x32x16_bf16(a, b, c, 0, 0, 0);
}

__device__ __forceinline__ void gload16(const void* g, void* l) {
  __builtin_amdgcn_global_load_lds(
      (const __attribute__((address_space(1))) unsigned int*)g,
      (__attribute__((address_space(3))) unsigned int*)l, 16, 0, 0);
}

__device__ __forceinline__ u32 cvtpk(float lo, float hi) {
  u32 r;
  asm volatile("v_cvt_pk_bf16_f32 %0, %1, %2" : "=v"(r) : "v"(lo), "v"(hi));
  return r;
}
__device__ __forceinline__ void pl32swap(u32& a, u32& b) {
  asm volatile("v_permlane32_swap_b32 %0, %1" : "+v"(a), "+v"(b));
}

// ---------------- pack kernels ----------------

__global__ void pack_x_kernel(const float* __restrict__ x, u16* __restrict__ xb) {
  const int i = blockIdx.x * 256 + threadIdx.x;
  const float4 v = ((const float4*)x)[i];
  u16x4 o;
  o[0] = f2bf(v.x); o[1] = f2bf(v.y); o[2] = f2bf(v.z); o[3] = f2bf(v.w);
  ((u16x4*)xb)[i] = o;
}

// W: [512][4096] col = k*8+h  ->  Wp: [h*512+k][dd]  (tiled LDS transpose)
__global__ void pack_wqkv_t(const float* __restrict__ W, u16* __restrict__ Wp) {
  __shared__ u16 tile[64][72];
  const int t = threadIdx.x;
  const int c0 = blockIdx.x * 64, dd0 = blockIdx.y * 64;
#pragma unroll
  for (int s = 0; s < 4; ++s) {
    const int r = s * 16 + (t >> 4);
    const int q = (t & 15) * 4;
    const float4 v = *(const float4*)&W[(size_t)(dd0 + r) * 4096 + c0 + q];
    tile[r][q + 0] = f2bf(v.x); tile[r][q + 1] = f2bf(v.y);
    tile[r][q + 2] = f2bf(v.z); tile[r][q + 3] = f2bf(v.w);
  }
  __syncthreads();
#pragma unroll
  for (int s = 0; s < 4; ++s) {
    const int cl = s * 16 + (t >> 4);
    const int u = t & 15;
    const int cg = c0 + cl;
    const int orow = (cg & 7) * 512 + (cg >> 3);
    u16x4 o;
#pragma unroll
    for (int i = 0; i < 4; ++i) o[i] = tile[u * 4 + i][cl];
    *(u16x4*)&Wp[(size_t)orow * 512 + dd0 + u * 4] = o;
  }
}

// Wo: [4096][512] -> Wot: [n=512][k=4096]
__global__ void pack_wo_t(const float* __restrict__ W, u16* __restrict__ Wp) {
  __shared__ u16 tile[64][72];
  const int t = threadIdx.x;
  const int k0 = blockIdx.x * 64, n0 = blockIdx.y * 64;
#pragma unroll
  for (int s = 0; s < 4; ++s) {
    const int r = s * 16 + (t >> 4);
    const int q = (t & 15) * 4;
    const float4 v = *(const float4*)&W[(size_t)(k0 + r) * 512 + n0 + q];
    tile[r][q + 0] = f2bf(v.x); tile[r][q + 1] = f2bf(v.y);
    tile[r][q + 2] = f2bf(v.z); tile[r][q + 3] = f2bf(v.w);
  }
  __syncthreads();
#pragma unroll
  for (int s = 0; s < 4; ++s) {
    const int cl = s * 16 + (t >> 4);
    const int u = t & 15;
    u16x4 o;
#pragma unroll
    for (int i = 0; i < 4; ++i) o[i] = tile[u * 4 + i][cl];
    *(u16x4*)&Wp[(size_t)(n0 + cl) * 4096 + k0 + u * 4] = o;
  }
}

// ---------------- GEMM: C[M][N] = A[M][Kd] * B[N][Kd]^T ----------------

template <int MODE>
__global__ __launch_bounds__(256, 2) void gemm_bf16(
    const u16* __restrict__ A, const u16* __restrict__ B,
    void* __restrict__ Cout, const float* __restrict__ bias,
    int Kd, float scale) {
  __shared__ u16 Al[128 * 64];
  __shared__ u16 Bl[128 * 64];
  const int tid = threadIdx.x;
  const int lane = tid & 63;
  const int w = tid >> 6, wm = w >> 1, wn = w & 1;
  const int l15 = lane & 15, lg = lane >> 4;
  const int m0 = blockIdx.y * 128, n0 = blockIdx.x * 128;

  f32x4 acc[4][4];
  const f32x4 zero = {0.f, 0.f, 0.f, 0.f};
#pragma unroll
  for (int i = 0; i < 4; ++i)
#pragma unroll
    for (int j = 0; j < 4; ++j) acc[i][j] = zero;

  const int nk = Kd >> 6;
  for (int kt = 0; kt < nk; ++kt) {
    __syncthreads();
    const int k0 = kt << 6;
#pragma unroll
    for (int s = 0; s < 4; ++s) {
      const int chunk = s * 256 + tid;
      const int row = chunk >> 3, c = chunk & 7;
      const int cs = c ^ (row & 7);
      gload16(A + (size_t)(m0 + row) * Kd + k0 + cs * 8, &Al[chunk * 8]);
    }
#pragma unroll
    for (int s = 0; s < 4; ++s) {
      const int chunk = s * 256 + tid;
      const int row = chunk >> 3, c = chunk & 7;
      const int cs = c ^ (row & 7);
      gload16(B + (size_t)(n0 + row) * Kd + k0 + cs * 8, &Bl[chunk * 8]);
    }
    __syncthreads();
#pragma unroll
    for (int kk = 0; kk < 2; ++kk) {
      bf16x8 af[4], bfr[4];
      const int ch = kk * 4 + lg;
#pragma unroll
      for (int i = 0; i < 4; ++i) {
        const int ar = wm * 64 + i * 16 + l15;
        af[i] = *(const bf16x8*)&Al[ar * 64 + ((ch ^ (ar & 7)) * 8)];
        const int br = wn * 64 + i * 16 + l15;
        bfr[i] = *(const bf16x8*)&Bl[br * 64 + ((ch ^ (br & 7)) * 8)];
      }
#pragma unroll
      for (int i = 0; i < 4; ++i)
#pragma unroll
        for (int j = 0; j < 4; ++j)
          acc[i][j] = mfma16(af[i], bfr[j], acc[i][j]);
    }
  }

#pragma unroll
  for (int i = 0; i < 4; ++i) {
    const int gr0 = m0 + wm * 64 + i * 16 + lg * 4;
#pragma unroll
    for (int j = 0; j < 4; ++j) {
      const int gc = n0 + wn * 64 + j * 16 + l15;
      if constexpr (MODE == 0) {
        u16* O = (u16*)Cout;
        const int h = gc >> 9, d = gc & 511;
#pragma unroll
        for (int r = 0; r < 4; ++r) {
          const int grr = gr0 + r;
          const int bb = grr >> 11, t = grr & 2047;
          O[((size_t)((bb * 8 + h) * 2048 + t) << 9) + d] = f2bf(acc[i][j][r] * scale);
        }
      } else if constexpr (MODE == 1) {
        u16* O = (u16*)Cout;
        const int h = gc >> 9, d = gc & 511;
        const int bb = gr0 >> 11, t = gr0 & 2047;
        u16x4 pk;
#pragma unroll
        for (int r = 0; r < 4; ++r) pk[r] = f2bf(acc[i][j][r]);
        *(u16x4*)&O[((size_t)((bb * 8 + h) * 512 + d) << 11) + t] = pk;
      } else {
        float* O = (float*)Cout;
        const float bv = bias[gc];
#pragma unroll
        for (int r = 0; r < 4; ++r)
          O[(size_t)(gr0 + r) * 512 + gc] = acc[i][j][r] + bv;
      }
    }
  }
}

// ---------------- flash attention v10: KVB=64, r6 convoy discipline ----------------
// Q,K: [bh][2048][512]; Vt: [bh][512][2048]; Og: [bb*2048+t][h*512+d]
// block = 8 waves = 4 pairs; pair owns 32 q rows (128 q/block); wave k/d-half = 256.
// KV block 64, 32 steps. LDS = K[64][512] 64K + Vt[512][64] 64K + Sxf 32K = 160K.
// Per step: QKT (2 indep chains st0,st1) | seq f32 exchange (st0 then st1, Sxf reused)
// | softmax over 64 kv | PV 32 mfma. Staging split-phase: SK(t+1) after B1 (K dead),
// SV(t+1) after B5 (V dead); counted vmcnt BEFORE barriers (cross-wave safe, r8 fix):
// B4 vmcnt(8) drains SV(t) [oldest], B6 vmcnt(8) drains SK(t+1). Tails: t=31 vmcnt(0).

__global__ __launch_bounds__(512, 2) void attn_kernel(
    const u16* __restrict__ Qg, const u16* __restrict__ Kg,
    const u16* __restrict__ Vtg, u16* __restrict__ Og, int nbh_pxcd) {
  __shared__ u16 K_lds[64 * 512];   // [kv][k]  chunk swz: c ^ (kv&31)
  __shared__ u16 Vt_lds[512 * 64];  // [d][kv]  chunk swz: c ^ (d&7)
  __shared__ float Sxf[8][32][32];  // per-wave 16-f32 exchange, slot-swizzled, reused 2x

  const int tid = threadIdx.x;
  const int lane = tid & 63;
  const int w = tid >> 6;
  const int pr = w >> 1, whalf = w & 1;
  const int l31 = lane & 31, hi = lane >> 5;

  const int bid = blockIdx.x;
  const int x8 = bid & 7, rest = bid >> 3;
  const int qt = rest & 15;
  const int bh = x8 * nbh_pxcd + (rest >> 4);

  const u16* Qb = Qg + (size_t)bh * 2048 * 512;
  const u16* Kb = Kg + (size_t)bh * 2048 * 512;
  const u16* Vb = Vtg + (size_t)bh * 2048 * 512;

  // Q as B-fragments: lane holds Q[q = l31][k = whalf*256 + c*16 + hi*8 + j]
  const int qrow = qt * 128 + pr * 32 + l31;
  bf16x8 qf[16];
  {
    const u16* qp = Qb + (size_t)qrow * 512 + whalf * 256 + hi * 8;
#pragma unroll
    for (int c = 0; c < 16; ++c) qf[c] = *(const bf16x8*)(qp + c * 16);
  }

  f32x16 acc[8];
#pragma unroll
  for (int i = 0; i < 8; ++i) acc[i] = {};
  float m = -1e30f, lsum = 0.f;

#define STAGE_K64(tile)                                                       \
  {                                                                           \
    _Pragma("unroll") for (int s_ = 0; s_ < 8; ++s_) {                        \
      const int chunk = s_ * 512 + tid;                                       \
      const int row = chunk >> 6, c_ = chunk & 63;                            \
      const int cs = c_ ^ (row & 31);                                         \
      gload16(Kb + (size_t)((tile) * 64 + row) * 512 + cs * 8,                \
              &K_lds[chunk * 8]);                                             \
    }                                                                         \
  }
#define STAGE_V64(tile)                                                       \
  {                                                                           \
    _Pragma("unroll") for (int s_ = 0; s_ < 8; ++s_) {                        \
      const int chunk = s_ * 512 + tid;                                       \
      const int row = chunk >> 3, c_ = chunk & 7;                             \
      const int cs = c_ ^ (row & 7);                                          \
      gload16(Vb + (size_t)row * 2048 + (tile) * 64 + cs * 8,                 \
              &Vt_lds[chunk * 8]);                                            \
    }                                                                         \
  }
#define LGKM_BAR()                                                            \
  asm volatile("s_waitcnt lgkmcnt(0)" ::: "memory");                          \
  __builtin_amdgcn_s_barrier();                                               \
  __builtin_amdgcn_sched_barrier(0);

  // -------- prologue --------
  STAGE_K64(0);
  STAGE_V64(0);
  asm volatile("s_waitcnt vmcnt(0)" ::: "memory");
  __builtin_amdgcn_s_barrier();
  __builtin_amdgcn_sched_barrier(0);

  for (int t = 0; t < 32; ++t) {
    // ---- QKT(t): two independent chains over kv halves ----
    f32x16 st0 = {}, st1 = {};
    __builtin_amdgcn_s_setprio(1);
#pragma unroll
    for (int c = 0; c < 16; ++c) {
      const int j = whalf * 32 + 2 * c + hi;
      const int pos = j ^ l31;
      bf16x8 kf0 = *(const bf16x8*)&K_lds[l31 * 512 + pos * 8];
      bf16x8 kf1 = *(const bf16x8*)&K_lds[(32 + l31) * 512 + pos * 8];
      st0 = mfma32(kf0, qf[c], st0);
      st1 = mfma32(kf1, qf[c], st1);
    }
    __builtin_amdgcn_s_setprio(0);

    // ---- exchange st0 (f32, slot-swizzled) ----
    {
      float* sp = &Sxf[w][l31][0];
#pragma unroll
      for (int g = 0; g < 4; ++g) {
        const int slot = (2 * g + hi) ^ (l31 & 7);
        f32x4 v = {st0[4 * g + 0], st0[4 * g + 1], st0[4 * g + 2], st0[4 * g + 3]};
        *(f32x4*)&sp[slot * 4] = v;
      }
    }
    LGKM_BAR();  // B1: st0 visible; all QKT K-reads retired -> K_lds free
    if (t < 31) STAGE_K64(t + 1);
    {
      const float* sp = &Sxf[w ^ 1][l31][0];
#pragma unroll
      for (int g = 0; g < 4; ++g) {
        const int slot = (2 * g + hi) ^ (l31 & 7);
        const f32x4 v = *(const f32x4*)&sp[slot * 4];
#pragma unroll
        for (int jj = 0; jj < 4; ++jj) st0[4 * g + jj] += v[jj];
      }
    }
    LGKM_BAR();  // B2: all st0 reads done -> Sxf reusable

    // ---- exchange st1 ----
    {
      float* sp = &Sxf[w][l31][0];
#pragma unroll
      for (int g = 0; g < 4; ++g) {
        const int slot = (2 * g + hi) ^ (l31 & 7);
        f32x4 v = {st1[4 * g + 0], st1[4 * g + 1], st1[4 * g + 2], st1[4 * g + 3]};
        *(f32x4*)&sp[slot * 4] = v;
      }
    }
    LGKM_BAR();  // B3: st1 visible
    {
      const float* sp = &Sxf[w ^ 1][l31][0];
#pragma unroll
      for (int g = 0; g < 4; ++g) {
        const int slot = (2 * g + hi) ^ (l31 & 7);
        const f32x4 v = *(const f32x4*)&sp[slot * 4];
#pragma unroll
        for (int jj = 0; jj < 4; ++jj) st1[4 * g + jj] += v[jj];
      }
    }

    // ---- online softmax over 64 kv (lane owns q = l31) ----
    {
      float mx = st0[0];
#pragma unroll
      for (int r = 1; r < 16; ++r) mx = fmaxf(mx, st0[r]);
#pragma unroll
      for (int r = 0; r < 16; ++r) mx = fmaxf(mx, st1[r]);
      mx = fmaxf(mx, __shfl_xor(mx, 32, 64));
      const float mnew = fmaxf(m, mx);
      if (__any(mnew > m)) {
        const float al = __expf(m - mnew);
#pragma unroll
        for (int z = 0; z < 8; ++z) acc[z] *= al;
        lsum *= al;
        m = mnew;
      }
#pragma unroll
      for (int r = 0; r < 16; ++r) {
        st0[r] = __expf(st0[r] - m);
        lsum += st0[r];
      }
#pragma unroll
      for (int r = 0; r < 16; ++r) {
        st1[r] = __expf(st1[r] - m);
        lsum += st1[r];
      }
    }

    // ---- P -> B-fragments (T12 twice): pf[0..1] kv 0-31, pf[2..3] kv 32-63 ----
    bf16x8 pf[4];
    {
      u32 wd[8];
#pragma unroll
      for (int g = 0; g < 4; ++g) {
        wd[2 * g] = cvtpk(st0[4 * g + 0], st0[4 * g + 1]);
        wd[2 * g + 1] = cvtpk(st0[4 * g + 2], st0[4 * g + 3]);
      }
      pl32swap(wd[0], wd[2]); pl32swap(wd[1], wd[3]);
      pl32swap(wd[4], wd[6]); pl32swap(wd[5], wd[7]);
      u32x4 f0 = {wd[0], wd[1], wd[2], wd[3]};
      u32x4 f1 = {wd[4], wd[5], wd[6], wd[7]};
      pf[0] = __builtin_bit_cast(bf16x8, f0);
      pf[1] = __builtin_bit_cast(bf16x8, f1);
#pragma unroll
      for (int g = 0; g < 4; ++g) {
        wd[2 * g] = cvtpk(st1[4 * g + 0], st1[4 * g + 1]);
        wd[2 * g + 1] = cvtpk(st1[4 * g + 2], st1[4 * g + 3]);
      }
      pl32swap(wd[0], wd[2]); pl32swap(wd[1], wd[3]);
      pl32swap(wd[4], wd[6]); pl32swap(wd[5], wd[7]);
      u32x4 f2 = {wd[0], wd[1], wd[2], wd[3]};
      u32x4 f3 = {wd[4], wd[5], wd[6], wd[7]};
      pf[2] = __builtin_bit_cast(bf16x8, f2);
      pf[3] = __builtin_bit_cast(bf16x8, f3);
    }

    // ---- pre-PV drain: SV(t) must be resident (oldest 8 in flight) ----
    if (t < 31) {
      asm volatile("s_waitcnt vmcnt(8)" ::: "memory");
    } else {
      asm volatile("s_waitcnt vmcnt(0)" ::: "memory");
    }
    __builtin_amdgcn_s_barrier();  // B4
    __builtin_amdgcn_sched_barrier(0);

    // ---- PV(t): O^T += V^T · P ----
    __builtin_amdgcn_s_setprio(1);
#pragma unroll
    for (int blk = 0; blk < 8; ++blk) {
      const int drow = whalf * 256 + blk * 32 + l31;
#pragma unroll
      for (int kc = 0; kc < 4; ++kc) {
        const int pos = (2 * kc + hi) ^ (drow & 7);
        bf16x8 vf = *(const bf16x8*)&Vt_lds[drow * 64 + pos * 8];
        acc[blk] = mfma32(vf, pf[kc], acc[blk]);
      }
    }
    __builtin_amdgcn_s_setprio(0);
    LGKM_BAR();  // B5: all PV V-reads retired -> Vt_lds free

    // ---- stage SV(t+1) + end drain (SK(t+1) must land before next QKT) ----
    if (t < 31) {
      STAGE_V64(t + 1);
      asm volatile("s_waitcnt vmcnt(8)" ::: "memory");
    } else {
      asm volatile("s_waitcnt vmcnt(0)" ::: "memory");
    }
    __builtin_amdgcn_s_barrier();  // B6
    __builtin_amdgcn_sched_barrier(0);
  }

  // -------- finalize --------
  lsum += __shfl_xor(lsum, 32, 64);
  const float inv = 1.0f / lsum;
  const int bb = bh >> 3, h = bh & 7;
  const int t = qt * 128 + pr * 32 + l31;
  u16* orow_p = Og + (size_t)(bb * 2048 + t) * 4096 + h * 512;
#pragma unroll
  for (int blk = 0; blk < 8; ++blk) {
    const int dbase = whalf * 256 + blk * 32 + 4 * hi;
#pragma unroll
    for (int g = 0; g < 4; ++g) {
      u16x4 pk;
#pragma unroll
      for (int z = 0; z < 4; ++z) pk[z] = f2bf(acc[blk][4 * g + z] * inv);
      *(u16x4*)(orow_p + dbase + 8 * g) = pk;
    }
  }
#undef STAGE_K64
#undef STAGE_V64
#undef LGKM_BAR
}

// ---------------- launcher ----------------

extern "C" void kernel_launch(void* const* d_in, const int* in_sizes, int n_in,
                              void* d_out, int out_size, void* d_ws, size_t ws_size,
                              hipStream_t stream) {
  const float* x = (const float*)d_in[0];
  const float* Wq = (const float*)d_in[1];
  const float* Wk = (const float*)d_in[2];
  const float* Wv = (const float*)d_in[3];
  const float* Wo = (const float*)d_in[4];
  const float* bo = (const float*)d_in[5];
  float* out = (float*)d_out;

  const size_t MB = 1ull << 20;
  int BB;
  if (ws_size >= 280 * MB) BB = 4;
  else if (ws_size >= 152 * MB) BB = 2;
  else BB = 1;

  char* ws = (char*)d_ws;
  u16* xb  = (u16*)(ws);
  u16* Wqp = (u16*)(ws + 8 * MB);
  u16* Wkp = (u16*)(ws + 12 * MB);
  u16* Wvp = (u16*)(ws + 16 * MB);
  u16* Wot = (u16*)(ws + 20 * MB);
  u16* Qg  = (u16*)(ws + 24 * MB);
  u16* Kg  = (u16*)(ws + (24 + 16 * BB) * MB);
  u16* Vtg = (u16*)(ws + (24 + 32 * BB) * MB);
  u16* Og  = (u16*)(ws + (24 + 48 * BB) * MB);

  pack_x_kernel<<<dim3(4096), dim3(256), 0, stream>>>(x, xb);
  pack_wqkv_t<<<dim3(64, 8), dim3(256), 0, stream>>>(Wq, Wqp);
  pack_wqkv_t<<<dim3(64, 8), dim3(256), 0, stream>>>(Wk, Wkp);
  pack_wqkv_t<<<dim3(64, 8), dim3(256), 0, stream>>>(Wv, Wvp);
  pack_wo_t<<<dim3(64, 8), dim3(256), 0, stream>>>(Wo, Wot);

  const float qk_scale = 0.21022410381342865f;  // 1 / 512^0.25

  const int nchunk = 4 / BB;
  for (int c = 0; c < nchunk; ++c) {
    const u16* Ax = xb + (size_t)c * BB * 2048 * 512;
    gemm_bf16<0><<<dim3(32, BB * 16), dim3(256), 0, stream>>>(Ax, Wqp, (void*)Qg, nullptr, 512, qk_scale);
    gemm_bf16<0><<<dim3(32, BB * 16), dim3(256), 0, stream>>>(Ax, Wkp, (void*)Kg, nullptr, 512, qk_scale);
    gemm_bf16<1><<<dim3(32, BB * 16), dim3(256), 0, stream>>>(Ax, Wvp, (void*)Vtg, nullptr, 512, 1.0f);

    attn_kernel<<<dim3(16 * BB * 8), dim3(512), 0, stream>>>(Qg, Kg, Vtg, Og, BB);

    gemm_bf16<2><<<dim3(4, BB * 16), dim3(256), 0, stream>>>(
        Og, Wot, (void*)(out + (size_t)c * BB * 2048 * 512), bo, 4096, 1.0f);
  }
}

// Round 12
// 562.649 us; speedup vs baseline: 3.1387x; 3.1387x over previous
//
#include <hip/hip_runtime.h>

typedef unsigned short u16;
typedef unsigned char u8;
typedef unsigned int u32;
typedef long i64;
typedef __attribute__((ext_vector_type(8))) short bf16x8;
typedef __attribute__((ext_vector_type(4))) float f32x4;
typedef __attribute__((ext_vector_type(16))) float f32x16;
typedef __attribute__((ext_vector_type(4))) u16 u16x4;
typedef __attribute__((ext_vector_type(4))) u32 u32x4;

__device__ __forceinline__ u16 f2bf(float f) {
  u32 u = __builtin_bit_cast(u32, f);
  return (u16)((u + 0x7FFFu + ((u >> 16) & 1u)) >> 16);
}
__device__ __forceinline__ u8 f2fp8(float f) {
  int w = __builtin_amdgcn_cvt_pk_fp8_f32(f, 0.f, 0, false);
  return (u8)(w & 0xff);
}

__device__ __forceinline__ f32x4 mfma16(bf16x8 a, bf16x8 b, f32x4 c) {
  return __builtin_amdgcn_mfma_f32_16x16x32_bf16(a, b, c, 0, 0, 0);
}
__device__ __forceinline__ f32x16 mfma32(bf16x8 a, bf16x8 b, f32x16 c) {
  return __builtin_amdgcn_mfma_f32_32x32x16_bf16(a, b, c, 0, 0, 0);
}
__device__ __forceinline__ f32x16 mfma32f8(i64 a, i64 b, f32x16 c) {
  return __builtin_amdgcn_mfma_f32_32x32x16_fp8_fp8(a, b, c, 0, 0, 0);
}

__device__ __forceinline__ void gload16(const void* g, void* l) {
  __builtin_amdgcn_global_load_lds(
      (const __attribute__((address_space(1))) unsigned int*)g,
      (__attribute__((address_space(3))) unsigned int*)l, 16, 0, 0);
}

__device__ __forceinline__ u32 cvtpk(float lo, float hi) {
  u32 r;
  asm volatile("v_cvt_pk_bf16_f32 %0, %1, %2" : "=v"(r) : "v"(lo), "v"(hi));
  return r;
}
__device__ __forceinline__ void pl32swap(u32& a, u32& b) {
  asm volatile("v_permlane32_swap_b32 %0, %1" : "+v"(a), "+v"(b));
}

// ---------------- pack kernels ----------------

__global__ void pack_x_kernel(const float* __restrict__ x, u16* __restrict__ xb) {
  const int i = blockIdx.x * 256 + threadIdx.x;
  const float4 v = ((const float4*)x)[i];
  u16x4 o;
  o[0] = f2bf(v.x); o[1] = f2bf(v.y); o[2] = f2bf(v.z); o[3] = f2bf(v.w);
  ((u16x4*)xb)[i] = o;
}

// W: [512][4096] col = k*8+h  ->  Wp: [h*512+k][dd]  (tiled LDS transpose)
__global__ void pack_wqkv_t(const float* __restrict__ W, u16* __restrict__ Wp) {
  __shared__ u16 tile[64][72];
  const int t = threadIdx.x;
  const int c0 = blockIdx.x * 64, dd0 = blockIdx.y * 64;
#pragma unroll
  for (int s = 0; s < 4; ++s) {
    const int r = s * 16 + (t >> 4);
    const int q = (t & 15) * 4;
    const float4 v = *(const float4*)&W[(size_t)(dd0 + r) * 4096 + c0 + q];
    tile[r][q + 0] = f2bf(v.x); tile[r][q + 1] = f2bf(v.y);
    tile[r][q + 2] = f2bf(v.z); tile[r][q + 3] = f2bf(v.w);
  }
  __syncthreads();
#pragma unroll
  for (int s = 0; s < 4; ++s) {
    const int cl = s * 16 + (t >> 4);
    const int u = t & 15;
    const int cg = c0 + cl;
    const int orow = (cg & 7) * 512 + (cg >> 3);
    u16x4 o;
#pragma unroll
    for (int i = 0; i < 4; ++i) o[i] = tile[u * 4 + i][cl];
    *(u16x4*)&Wp[(size_t)orow * 512 + dd0 + u * 4] = o;
  }
}

// Wo: [4096][512] -> Wot: [n=512][k=4096]
__global__ void pack_wo_t(const float* __restrict__ W, u16* __restrict__ Wp) {
  __shared__ u16 tile[64][72];
  const int t = threadIdx.x;
  const int k0 = blockIdx.x * 64, n0 = blockIdx.y * 64;
#pragma unroll
  for (int s = 0; s < 4; ++s) {
    const int r = s * 16 + (t >> 4);
    const int q = (t & 15) * 4;
    const float4 v = *(const float4*)&W[(size_t)(k0 + r) * 512 + n0 + q];
    tile[r][q + 0] = f2bf(v.x); tile[r][q + 1] = f2bf(v.y);
    tile[r][q + 2] = f2bf(v.z); tile[r][q + 3] = f2bf(v.w);
  }
  __syncthreads();
#pragma unroll
  for (int s = 0; s < 4; ++s) {
    const int cl = s * 16 + (t >> 4);
    const int u = t & 15;
    u16x4 o;
#pragma unroll
    for (int i = 0; i < 4; ++i) o[i] = tile[u * 4 + i][cl];
    *(u16x4*)&Wp[(size_t)(n0 + cl) * 4096 + k0 + u * 4] = o;
  }
}

// ---------------- GEMM: C[M][N] = A[M][Kd] * B[N][Kd]^T ----------------
// MODE 0: fp8 -> [bh][t][d] (*scale)            (Q, K)
// MODE 1: bf16 transposed -> Vt [bh][d][t]      (V)
// MODE 2: fp32 + bias -> [row][512]             (out)

template <int MODE>
__global__ __launch_bounds__(256, 2) void gemm_bf16(
    const u16* __restrict__ A, const u16* __restrict__ B,
    void* __restrict__ Cout, const float* __restrict__ bias,
    int Kd, float scale) {
  __shared__ u16 Al[128 * 64];
  __shared__ u16 Bl[128 * 64];
  const int tid = threadIdx.x;
  const int lane = tid & 63;
  const int w = tid >> 6, wm = w >> 1, wn = w & 1;
  const int l15 = lane & 15, lg = lane >> 4;
  const int m0 = blockIdx.y * 128, n0 = blockIdx.x * 128;

  f32x4 acc[4][4];
  const f32x4 zero = {0.f, 0.f, 0.f, 0.f};
#pragma unroll
  for (int i = 0; i < 4; ++i)
#pragma unroll
    for (int j = 0; j < 4; ++j) acc[i][j] = zero;

  const int nk = Kd >> 6;
  for (int kt = 0; kt < nk; ++kt) {
    __syncthreads();
    const int k0 = kt << 6;
#pragma unroll
    for (int s = 0; s < 4; ++s) {
      const int chunk = s * 256 + tid;
      const int row = chunk >> 3, c = chunk & 7;
      const int cs = c ^ (row & 7);
      gload16(A + (size_t)(m0 + row) * Kd + k0 + cs * 8, &Al[chunk * 8]);
    }
#pragma unroll
    for (int s = 0; s < 4; ++s) {
      const int chunk = s * 256 + tid;
      const int row = chunk >> 3, c = chunk & 7;
      const int cs = c ^ (row & 7);
      gload16(B + (size_t)(n0 + row) * Kd + k0 + cs * 8, &Bl[chunk * 8]);
    }
    __syncthreads();
#pragma unroll
    for (int kk = 0; kk < 2; ++kk) {
      bf16x8 af[4], bfr[4];
      const int ch = kk * 4 + lg;
#pragma unroll
      for (int i = 0; i < 4; ++i) {
        const int ar = wm * 64 + i * 16 + l15;
        af[i] = *(const bf16x8*)&Al[ar * 64 + ((ch ^ (ar & 7)) * 8)];
        const int br = wn * 64 + i * 16 + l15;
        bfr[i] = *(const bf16x8*)&Bl[br * 64 + ((ch ^ (br & 7)) * 8)];
      }
#pragma unroll
      for (int i = 0; i < 4; ++i)
#pragma unroll
        for (int j = 0; j < 4; ++j)
          acc[i][j] = mfma16(af[i], bfr[j], acc[i][j]);
    }
  }

#pragma unroll
  for (int i = 0; i < 4; ++i) {
    const int gr0 = m0 + wm * 64 + i * 16 + lg * 4;
#pragma unroll
    for (int j = 0; j < 4; ++j) {
      const int gc = n0 + wn * 64 + j * 16 + l15;
      if constexpr (MODE == 0) {
        u8* O = (u8*)Cout;
        const int h = gc >> 9, d = gc & 511;
#pragma unroll
        for (int r = 0; r < 4; ++r) {
          const int grr = gr0 + r;
          const int bb = grr >> 11, t = grr & 2047;
          O[((size_t)((bb * 8 + h) * 2048 + t) << 9) + d] = f2fp8(acc[i][j][r] * scale);
        }
      } else if constexpr (MODE == 1) {
        u16* O = (u16*)Cout;
        const int h = gc >> 9, d = gc & 511;
        const int bb = gr0 >> 11, t = gr0 & 2047;
        u16x4 pk;
#pragma unroll
        for (int r = 0; r < 4; ++r) pk[r] = f2bf(acc[i][j][r]);
        *(u16x4*)&O[((size_t)((bb * 8 + h) * 512 + d) << 11) + t] = pk;
      } else {
        float* O = (float*)Cout;
        const float bv = bias[gc];
#pragma unroll
        for (int r = 0; r < 4; ++r)
          O[(size_t)(gr0 + r) * 512 + gc] = acc[i][j][r] + bv;
      }
    }
  }
}

// ---------------- flash attention v12: r6 structure, fp8 QK^T, bf16 PV ----------------
// Q,K fp8: [bh][2048][512]B; Vt bf16: [bh][512][2048]; Og bf16: [bb*2048+t][h*512+d]
// block = 8 waves = 4 pairs; pair owns 32 q rows (128 q/block); wave k/d-half = 256.
// KV block 32, 64 steps. LDS = K8 dbuf 2x16K + Vt dbuf 2x32K + Sxf 32K = 131072 B.
// Pacing = r6 (proven convoy): stage K(t+1)+V(t+1) at step START into buf^1,
// single vmcnt(0) drain + barrier at step END. 2 barriers/step.

__global__ __launch_bounds__(512, 2) void attn_kernel(
    const u8* __restrict__ Qg, const u8* __restrict__ Kg,
    const u16* __restrict__ Vtg, u16* __restrict__ Og, int nbh_pxcd) {
  __shared__ u8 K8[2][32 * 512];       // [buf][kv][k]B  16B-chunk swz: c ^ row (32 chunks/row)
  __shared__ u16 Vt_lds[2][512 * 32];  // [buf][d][kv]   8-u16-chunk swz: c ^ ((d>>1)&3)
  __shared__ float Sxf[8][32][32];     // f32 pair exchange, slot-swizzled

  const int tid = threadIdx.x;
  const int lane = tid & 63;
  const int w = tid >> 6;
  const int pr = w >> 1, whalf = w & 1;
  const int l31 = lane & 31, hi = lane >> 5;

  // XCD-aware decode
  const int bid = blockIdx.x;
  const int x8 = bid & 7, rest = bid >> 3;
  const int qt = rest & 15;
  const int bh = x8 * nbh_pxcd + (rest >> 4);

  const u8* Qb = Qg + (size_t)bh * 2048 * 512;
  const u8* Kb = Kg + (size_t)bh * 2048 * 512;
  const u16* Vb = Vtg + (size_t)bh * 2048 * 512;

  // Q fp8 B-fragments: lane holds Q[q=l31][k = whalf*256 + cc*16 + hi*8 + j]
  const int qrow = qt * 128 + pr * 32 + l31;
  i64 qf8[16];
  {
    const u8* qp = Qb + (size_t)qrow * 512 + whalf * 256 + hi * 8;
#pragma unroll
    for (int cc = 0; cc < 16; ++cc) qf8[cc] = *(const i64*)(qp + cc * 16);
  }

  f32x16 acc[8];
#pragma unroll
  for (int i = 0; i < 8; ++i) acc[i] = {};
  float m = -1e30f, lsum = 0.f;

#define STAGE_K8(tile, buf)                                                   \
  {                                                                           \
    _Pragma("unroll") for (int s_ = 0; s_ < 2; ++s_) {                        \
      const int ch = s_ * 512 + tid;                                          \
      const int row = ch >> 5, c_ = ch & 31;                                  \
      const int cs = c_ ^ row;                                                \
      gload16(Kb + (size_t)((tile) * 32 + row) * 512 + cs * 16,               \
              &K8[buf][ch * 16]);                                             \
    }                                                                         \
  }
#define STAGE_V(tile, buf)                                                    \
  {                                                                           \
    _Pragma("unroll") for (int s_ = 0; s_ < 4; ++s_) {                        \
      const int chunk = s_ * 512 + tid;                                       \
      const int row = chunk >> 2, c_ = chunk & 3;                             \
      const int cs = c_ ^ ((row >> 1) & 3);                                   \
      gload16(Vb + (size_t)row * 2048 + (tile) * 32 + cs * 8,                 \
              &Vt_lds[buf][chunk * 8]);                                       \
    }                                                                         \
  }

  // -------- prologue: stage tile 0 --------
  STAGE_K8(0, 0);
  STAGE_V(0, 0);
  asm volatile("s_waitcnt vmcnt(0)" ::: "memory");
  __builtin_amdgcn_s_barrier();
  __builtin_amdgcn_sched_barrier(0);

  for (int step = 0; step < 64; ++step) {
    const int cur = step & 1;

    // phase 1: stage tiles(t+1) at step START (in flight across whole step)
    if (step < 63) {
      STAGE_K8(step + 1, cur ^ 1);
      STAGE_V(step + 1, cur ^ 1);
    }

    // phase 2: S^T partial = K_half · Q_half^T (fp8), rows=kv, cols=q
    f32x16 st = {};
    __builtin_amdgcn_s_setprio(1);
#pragma unroll
    for (int cc = 0; cc < 16; ++cc) {
      const int g = whalf * 16 + cc;              // logical 16B chunk (k-slice)
      const int pos = g ^ l31;                    // stored position (swz)
      i64 kf = *(const i64*)&K8[cur][l31 * 512 + pos * 16 + hi * 8];
      st = mfma32f8(kf, qf8[cc], st);
    }
    __builtin_amdgcn_s_setprio(0);

    // phase 3: pair exchange of partial S^T in f32
    {
      float* sp = &Sxf[w][l31][0];
#pragma unroll
      for (int g = 0; g < 4; ++g) {
        const int slot = (2 * g + hi) ^ (l31 & 7);
        f32x4 v = {st[4 * g + 0], st[4 * g + 1], st[4 * g + 2], st[4 * g + 3]};
        *(f32x4*)&sp[slot * 4] = v;
      }
    }
    asm volatile("s_waitcnt lgkmcnt(0)" ::: "memory");
    __builtin_amdgcn_s_barrier();
    __builtin_amdgcn_sched_barrier(0);
    float s[16];
    {
      const float* sp = &Sxf[w ^ 1][l31][0];
#pragma unroll
      for (int g = 0; g < 4; ++g) {
        const int slot = (2 * g + hi) ^ (l31 & 7);
        const f32x4 v = *(const f32x4*)&sp[slot * 4];
#pragma unroll
        for (int j = 0; j < 4; ++j) s[4 * g + j] = st[4 * g + j] + v[j];
      }
    }

    // phase 4: online softmax (lane owns q = l31; 16 of 32 kv)
    float mx = s[0];
#pragma unroll
    for (int r = 1; r < 16; ++r) mx = fmaxf(mx, s[r]);
    mx = fmaxf(mx, __shfl_xor(mx, 32, 64));
    const float mnew = fmaxf(m, mx);
    if (__any(mnew > m)) {
      const float al = __expf(m - mnew);
#pragma unroll
      for (int i = 0; i < 8; ++i) acc[i] *= al;
      lsum *= al;
      m = mnew;
    }
    float p[16];
#pragma unroll
    for (int r = 0; r < 16; ++r) {
      p[r] = __expf(s[r] - m);
      lsum += p[r];
    }

    // phase 5: P -> bf16 B-fragments (T12: cvt_pk + permlane32_swap)
    bf16x8 pf[2];
    {
      u32 wd[8];
#pragma unroll
      for (int g = 0; g < 4; ++g) {
        wd[2 * g] = cvtpk(p[4 * g + 0], p[4 * g + 1]);
        wd[2 * g + 1] = cvtpk(p[4 * g + 2], p[4 * g + 3]);
      }
      pl32swap(wd[0], wd[2]); pl32swap(wd[1], wd[3]);
      pl32swap(wd[4], wd[6]); pl32swap(wd[5], wd[7]);
      u32x4 f0 = {wd[0], wd[1], wd[2], wd[3]};
      u32x4 f1 = {wd[4], wd[5], wd[6], wd[7]};
      pf[0] = __builtin_bit_cast(bf16x8, f0);
      pf[1] = __builtin_bit_cast(bf16x8, f1);
    }

    // phase 6: O^T += V^T · P (bf16), rows=d (wave's 256-half), cols=q
    __builtin_amdgcn_s_setprio(1);
#pragma unroll
    for (int blk = 0; blk < 8; ++blk) {
      const int drow = whalf * 256 + blk * 32 + l31;
#pragma unroll
      for (int c2 = 0; c2 < 2; ++c2) {
        const int pos = (2 * c2 + hi) ^ ((drow >> 1) & 3);
        bf16x8 vf = *(const bf16x8*)&Vt_lds[cur][drow * 32 + pos * 8];
        acc[blk] = mfma32(vf, pf[c2], acc[blk]);
      }
    }
    __builtin_amdgcn_s_setprio(0);

    // phase 7: staging of t+1 complete & visible before next step
    asm volatile("s_waitcnt vmcnt(0)" ::: "memory");
    __builtin_amdgcn_s_barrier();
    __builtin_amdgcn_sched_barrier(0);
  }

  // -------- finalize --------
  lsum += __shfl_xor(lsum, 32, 64);
  const float inv = 1.0f / lsum;
  const int bb = bh >> 3, h = bh & 7;
  const int tq = qt * 128 + pr * 32 + l31;
  u16* orow_p = Og + (size_t)(bb * 2048 + tq) * 4096 + h * 512;
#pragma unroll
  for (int blk = 0; blk < 8; ++blk) {
    const int dbase = whalf * 256 + blk * 32 + 4 * hi;
#pragma unroll
    for (int g = 0; g < 4; ++g) {
      u16x4 pk;
#pragma unroll
      for (int z = 0; z < 4; ++z) pk[z] = f2bf(acc[blk][4 * g + z] * inv);
      *(u16x4*)(orow_p + dbase + 8 * g) = pk;
    }
  }
#undef STAGE_K8
#undef STAGE_V
}

// ---------------- launcher ----------------
// Per-batch: Q 8 + K 8 + Vt 16 + Og 16 = 48 MB.  ws need = 24 + 48*BB:
// BB=4 -> 216 MB, BB=2 -> 120 MB, BB=1 -> 72 MB.

extern "C" void kernel_launch(void* const* d_in, const int* in_sizes, int n_in,
                              void* d_out, int out_size, void* d_ws, size_t ws_size,
                              hipStream_t stream) {
  const float* x = (const float*)d_in[0];
  const float* Wq = (const float*)d_in[1];
  const float* Wk = (const float*)d_in[2];
  const float* Wv = (const float*)d_in[3];
  const float* Wo = (const float*)d_in[4];
  const float* bo = (const float*)d_in[5];
  float* out = (float*)d_out;

  const size_t MB = 1ull << 20;
  int BB;
  if (ws_size >= 216 * MB) BB = 4;
  else if (ws_size >= 120 * MB) BB = 2;
  else BB = 1;

  char* ws = (char*)d_ws;
  u16* xb  = (u16*)(ws);
  u16* Wqp = (u16*)(ws + 8 * MB);
  u16* Wkp = (u16*)(ws + 12 * MB);
  u16* Wvp = (u16*)(ws + 16 * MB);
  u16* Wot = (u16*)(ws + 20 * MB);
  u8*  Qg  = (u8*)(ws + 24 * MB);
  u8*  Kg  = (u8*)(ws + (24 + 8 * (size_t)BB) * MB);
  u16* Vtg = (u16*)(ws + (24 + 16 * (size_t)BB) * MB);
  u16* Og  = (u16*)(ws + (24 + 32 * (size_t)BB) * MB);

  pack_x_kernel<<<dim3(4096), dim3(256), 0, stream>>>(x, xb);
  pack_wqkv_t<<<dim3(64, 8), dim3(256), 0, stream>>>(Wq, Wqp);
  pack_wqkv_t<<<dim3(64, 8), dim3(256), 0, stream>>>(Wk, Wkp);
  pack_wqkv_t<<<dim3(64, 8), dim3(256), 0, stream>>>(Wv, Wvp);
  pack_wo_t<<<dim3(64, 8), dim3(256), 0, stream>>>(Wo, Wot);

  const float qk_scale = 0.21022410381342865f;  // 1 / 512^0.25

  const int nchunk = 4 / BB;
  for (int c = 0; c < nchunk; ++c) {
    const u16* Ax = xb + (size_t)c * BB * 2048 * 512;
    gemm_bf16<0><<<dim3(32, BB * 16), dim3(256), 0, stream>>>(Ax, Wqp, (void*)Qg, nullptr, 512, qk_scale);
    gemm_bf16<0><<<dim3(32, BB * 16), dim3(256), 0, stream>>>(Ax, Wkp, (void*)Kg, nullptr, 512, qk_scale);
    gemm_bf16<1><<<dim3(32, BB * 16), dim3(256), 0, stream>>>(Ax, Wvp, (void*)Vtg, nullptr, 512, 1.0f);

    attn_kernel<<<dim3(16 * BB * 8), dim3(512), 0, stream>>>(Qg, Kg, Vtg, Og, BB);

    gemm_bf16<2><<<dim3(4, BB * 16), dim3(256), 0, stream>>>(
        Og, Wot, (void*)(out + (size_t)c * BB * 2048 * 512), bo, 4096, 1.0f);
  }
}